// Round 4
// baseline (40364.883 us; speedup 1.0000x reference)
//
#include <hip/hip_runtime.h>

typedef _Float16 f16;
typedef _Float16 f16x8 __attribute__((ext_vector_type(8)));
typedef float f32x4 __attribute__((ext_vector_type(4)));

#define LN4 1.3862943611198906f

__device__ __forceinline__ void gl_lds16(const void* g, void* l) {
    typedef unsigned int u32;
    __builtin_amdgcn_global_load_lds(
        (const __attribute__((address_space(1))) u32*)(g),
        (__attribute__((address_space(3))) u32*)(l), 16, 0, 0);
}

// ===========================================================================
// Weight prep.
// 3-term layout: WT[d][tap][ h(CIN) | l(CIN) ] f16, d<CPAD, tap<28.
// plain layout:  WT[d][tap][ h(CIN) ] f16.
// ===========================================================================
__device__ void prep_split(int gid, int gsz, const float* __restrict__ W,
                           f16* __restrict__ dst, int CIN, int COUT, int CPAD)
{
    int total = CPAD * 28 * CIN;
    for (int i = gid; i < total; i += gsz) {
        int d = i / (28 * CIN);
        int rem = i - d * (28 * CIN);
        int tap = rem / CIN;
        int c = rem - tap * CIN;
        float v = (d < COUT && tap < 27) ? W[(size_t)(tap * CIN + c) * COUT + d] : 0.f;
        f16 h = (f16)v;
        size_t base = (size_t)d * (28 * 2 * CIN) + (size_t)tap * (2 * CIN);
        dst[base + c] = h;
        dst[base + CIN + c] = (f16)(v - (float)h);
    }
}

__device__ void prep_plain16(int gid, int gsz, const float* __restrict__ W,
                             f16* __restrict__ dst, int COUT)
{
    const int CIN = 16, CPAD = 16;
    int total = CPAD * 28 * CIN;
    for (int i = gid; i < total; i += gsz) {
        int d = i / (28 * CIN);
        int rem = i - d * (28 * CIN);
        int tap = rem / CIN;
        int c = rem - tap * CIN;
        float v = (d < COUT && tap < 27) ? W[(size_t)(tap * CIN + c) * COUT + d] : 0.f;
        dst[(size_t)d * (28 * CIN) + (size_t)tap * CIN + c] = (f16)v;
    }
}

__device__ void prep_pts(int gid, int gsz, const float* __restrict__ Wp,
                         const float* __restrict__ Ws, const float* __restrict__ Wt,
                         f16* __restrict__ dst)
{
    const int CIN = 16, CPAD = 16;
    int total = CPAD * 28 * CIN;
    for (int i = gid; i < total; i += gsz) {
        int d = i / (28 * CIN);
        int rem = i - d * (28 * CIN);
        int tap = rem / CIN;
        int c = rem - tap * CIN;
        float v = 0.f;
        if (tap < 27) {
            int kc = tap * CIN + c;
            if (d < 3)       v = Wp[(size_t)kc * 3 + d];
            else if (d < 5)  v = Ws[(size_t)kc * 2 + (d - 3)];
            else if (d < 10) v = Wt[(size_t)kc * 5 + (d - 5)];
        }
        dst[(size_t)d * (28 * CIN) + (size_t)tap * CIN + c] = (f16)v;
    }
}

__global__ __launch_bounds__(256) void prep_all_kernel(
    const float* W1, f16* WT1, const float* W1s, f16* WT1s,
    const float* W2, f16* WT2, const float* W3, f16* WT3,
    const float* W3p, const float* W3s, const float* W3t, f16* WTp)
{
    int gid = blockIdx.x * 256 + threadIdx.x;
    int gsz = gridDim.x * 256;
    prep_split(gid, gsz, W1, WT1, 80, 80, 80);
    prep_split(gid, gsz, W1s, WT1s, 80, 2, 16);
    prep_split(gid, gsz, W2, WT2, 48, 48, 48);
    prep_plain16(gid, gsz, W3, WT3, 16);
    prep_pts(gid, gsz, W3p, W3s, W3t, WTp);
}

// ===========================================================================
// Feature splits. 3-term: rows [h|l]; plain: rows [h]. Sentinel row at n==N.
// ===========================================================================
template<int CIN, bool SPLIT>
__global__ __launch_bounds__(256) void split_feat_kernel(
    const float* __restrict__ f, const float* __restrict__ mask,
    const int* __restrict__ parent, f16* __restrict__ Fc, int N)
{
    int i = blockIdx.x * 256 + threadIdx.x;
    if (i >= (N + 1) * CIN) return;
    int n = i / CIN;
    int c = i - n * CIN;
    float v = 0.f;
    if (n < N) {
        v = f[i];
        if (mask != nullptr) v *= mask[parent[n]];
    }
    if (SPLIT) {
        f16 h = (f16)v;
        Fc[(size_t)n * (2 * CIN) + c] = h;
        Fc[(size_t)n * (2 * CIN) + CIN + c] = (f16)(v - (float)h);
    } else {
        Fc[(size_t)n * CIN + c] = (f16)v;
    }
}

__global__ __launch_bounds__(256) void ppn_finalize_kernel(
    const int* __restrict__ coords, const float* __restrict__ s,
    float* __restrict__ ppn, float* __restrict__ mask, int N)
{
    int n = blockIdx.x * 256 + threadIdx.x;
    if (n >= N) return;
    float s0 = s[(size_t)n * 2 + 0], s1 = s[(size_t)n * 2 + 1];
    ppn[(size_t)n * 6 + 0] = (float)coords[(size_t)n * 4 + 0];
    ppn[(size_t)n * 6 + 1] = (float)coords[(size_t)n * 4 + 1];
    ppn[(size_t)n * 6 + 2] = (float)coords[(size_t)n * 4 + 2];
    ppn[(size_t)n * 6 + 3] = (float)coords[(size_t)n * 4 + 3];
    ppn[(size_t)n * 6 + 4] = s0;
    ppn[(size_t)n * 6 + 5] = s1;
    mask[n] = (s1 - s0 > LN4) ? 1.0f : 0.0f;
}

// ===========================================================================
// MFMA gather-conv. NT taps per K-slab, NTERMS in {3 (f16 split), 1 (f16)}.
// XOR-swizzled LDS (chunk' = (c&~7)|((c^row)&7)), idxS prefetch,
// global_load_lds staging. Epilogues: SPLIT (h|l out), F16, F32, SCATTER
// (scatter y·Wsc into sout[nbr] for Cout=2 score conv via atomics).
// ===========================================================================
enum { EPI_SPLIT = 0, EPI_F16 = 1, EPI_F32 = 2, EPI_SCAT = 3 };

template<int CIN, int NCT, int NT, int NTERMS, int NW, int EPI, int OUTC>
__global__ __launch_bounds__(NW * 64) void mfma_conv(
    const f16* __restrict__ F, const int* __restrict__ nbr,
    const f16* __restrict__ WT, float* __restrict__ outf,
    f16* __restrict__ oc, const float* __restrict__ Wsc,
    float* __restrict__ sout, int N, int nTiles)
{
    constexpr int BM = NW * 16;
    constexpr int BLK = NW * 64;
    constexpr int RB = (NTERMS == 3 ? 4 : 2) * CIN;  // bytes per tap-row
    constexpr int CPT = RB / 16;                     // chunks per tap-row
    constexpr int CPR = NT * CPT;                    // chunks per slab-row
    constexpr int PB = CPR * 16;                     // LDS slab-row pitch
    constexpr int KB = NT * CIN / 32;                // MFMA K-blocks per slab
    constexpr int COUT = NCT * 16;
    constexpr int P = 28 / NT;
    static_assert(CPR % 8 == 0, "swizzle needs 8-chunk groups");
    static_assert((BM * CPR) % 64 == 0 && (COUT * CPR) % 64 == 0, "wave granularity");

    __shared__ __align__(16) char AS[BM * PB];
    __shared__ __align__(16) char BS[COUT * PB];
    __shared__ int idxS[BM * 28];
    __shared__ float WsL[EPI == EPI_SCAT ? 27 * CIN * 2 : 1];

    const int t = threadIdx.x;
    const int lane = t & 63;
    const int l16 = lane & 15;
    const int quad = lane >> 4;
    const int band = t >> 6;

    int q8 = (nTiles + 7) >> 3;
    int tile = (blockIdx.x & 7) * q8 + (blockIdx.x >> 3);
    if (tile >= nTiles) return;
    const int m0 = tile * BM;

    for (int i = t; i < BM * 28; i += BLK) {
        int r = i / 28, tap = i - r * 28, row = m0 + r;
        idxS[i] = (row < N && tap < 27) ? nbr[(size_t)row * 27 + tap] : N;
    }
    if (EPI == EPI_SCAT)
        for (int i = t; i < 27 * CIN * 2; i += BLK) WsL[i] = Wsc[i];

    f32x4 acc[NCT];
    #pragma unroll
    for (int ct = 0; ct < NCT; ++ct) acc[ct] = (f32x4){0.f, 0.f, 0.f, 0.f};

    const int arow = band * 16 + l16;

    for (int p = 0; p < P; ++p) {
        __syncthreads();
        // stage B slab
        for (int i = t; i < COUT * CPR; i += BLK) {
            int d = i / CPR, cs = i - d * CPR;
            int c = (cs & ~7) | ((cs ^ d) & 7);
            int tp = c / CPT, cc = c - tp * CPT;
            gl_lds16((const char*)WT + ((size_t)d * 28 + NT * p + tp) * RB + cc * 16,
                     BS + (size_t)i * 16);
        }
        // stage gathered A slab
        for (int i = t; i < BM * CPR; i += BLK) {
            int r = i / CPR, cs = i - r * CPR;
            int c = (cs & ~7) | ((cs ^ r) & 7);
            int tp = c / CPT, cc = c - tp * CPT;
            int idx = idxS[r * 28 + NT * p + tp];
            gl_lds16((const char*)F + (size_t)idx * RB + cc * 16,
                     AS + (size_t)i * 16);
        }
        __syncthreads();
        // compute
        #pragma unroll
        for (int kb = 0; kb < KB; ++kb) {
            int ko = kb * 32 + quad * 8;
            int ts = ((CIN & (CIN - 1)) == 0) ? (ko / CIN) : (ko >= CIN ? 1 : 0);
            int ch = ts * CPT + (ko - ts * CIN) / 8;
            int sa = (ch & ~7) | ((ch ^ arow) & 7);
            f16x8 a_h = *(const f16x8*)(AS + arow * PB + sa * 16);
            f16x8 a_l;
            if (NTERMS == 3) {
                int chl = ch + CIN / 8;
                int sal = (chl & ~7) | ((chl ^ arow) & 7);
                a_l = *(const f16x8*)(AS + arow * PB + sal * 16);
            }
            #pragma unroll
            for (int ct = 0; ct < NCT; ++ct) {
                int drow = ct * 16 + l16;
                int sb = (ch & ~7) | ((ch ^ drow) & 7);
                f16x8 b_h = *(const f16x8*)(BS + drow * PB + sb * 16);
                acc[ct] = __builtin_amdgcn_mfma_f32_16x16x32_f16(a_h, b_h, acc[ct], 0, 0, 0);
                if (NTERMS == 3) {
                    int chl = ch + CIN / 8;
                    int sbl = (chl & ~7) | ((chl ^ drow) & 7);
                    f16x8 b_l = *(const f16x8*)(BS + drow * PB + sbl * 16);
                    acc[ct] = __builtin_amdgcn_mfma_f32_16x16x32_f16(a_l, b_h, acc[ct], 0, 0, 0);
                    acc[ct] = __builtin_amdgcn_mfma_f32_16x16x32_f16(a_h, b_l, acc[ct], 0, 0, 0);
                }
            }
        }
    }

    // ---- epilogues; D: row = quad*4+reg, col = lane&15 ----
    if (EPI == EPI_SCAT) {
        // s[nbr[n][k]] += y[n]·Wsc[26-k]  (Cout=2)
        #pragma unroll 1
        for (int tap = 0; tap < 27; ++tap) {
            const float* w = &WsL[(26 - tap) * CIN * 2];
            float q0[4] = {}, q1[4] = {};
            #pragma unroll
            for (int ct = 0; ct < NCT; ++ct) {
                float w0 = w[(ct * 16 + l16) * 2 + 0];
                float w1 = w[(ct * 16 + l16) * 2 + 1];
                #pragma unroll
                for (int r = 0; r < 4; ++r) {
                    q0[r] += acc[ct][r] * w0;
                    q1[r] += acc[ct][r] * w1;
                }
            }
            #pragma unroll
            for (int m = 1; m < 16; m <<= 1) {
                #pragma unroll
                for (int r = 0; r < 4; ++r) {
                    q0[r] += __shfl_xor(q0[r], m);
                    q1[r] += __shfl_xor(q1[r], m);
                }
            }
            if (l16 < 8) {
                int r = l16 >> 1, j = l16 & 1;
                float v0 = (r == 0) ? q0[0] : (r == 1) ? q0[1] : (r == 2) ? q0[2] : q0[3];
                float v1 = (r == 0) ? q1[0] : (r == 1) ? q1[1] : (r == 2) ? q1[2] : q1[3];
                float v = (j == 0) ? v0 : v1;
                int idx = idxS[(band * 16 + quad * 4 + r) * 28 + tap];
                atomicAdd(&sout[(size_t)idx * 2 + j], v);
            }
        }
    } else {
        #pragma unroll
        for (int ct = 0; ct < NCT; ++ct) {
            int col = ct * 16 + l16;
            #pragma unroll
            for (int r = 0; r < 4; ++r) {
                int row = m0 + band * 16 + quad * 4 + r;
                float v = acc[ct][r];
                if (EPI == EPI_SPLIT) {
                    if (row < N) {
                        f16 h = (f16)v;
                        oc[(size_t)row * (2 * COUT) + col] = h;
                        oc[(size_t)row * (2 * COUT) + COUT + col] = (f16)(v - (float)h);
                    } else if (row == N) {
                        oc[(size_t)row * (2 * COUT) + col] = (f16)0.f;
                        oc[(size_t)row * (2 * COUT) + COUT + col] = (f16)0.f;
                    }
                } else if (EPI == EPI_F16) {
                    if (row < N) oc[(size_t)row * COUT + col] = (f16)v;
                    else if (row == N) oc[(size_t)row * COUT + col] = (f16)0.f;
                } else {  // EPI_F32
                    if (row < N && col < OUTC)
                        outf[(size_t)row * OUTC + col] = v;
                }
            }
        }
    }
}

// ===========================================================================
extern "C" void kernel_launch(void* const* d_in, const int* in_sizes, int n_in,
                              void* d_out, int out_size, void* d_ws, size_t ws_size,
                              hipStream_t stream)
{
    const float* feat1 = (const float*)d_in[0];
    const float* feat2 = (const float*)d_in[1];
    const float* feat3 = (const float*)d_in[2];
    const float* W1    = (const float*)d_in[3];
    const float* W1s   = (const float*)d_in[4];
    const float* W2    = (const float*)d_in[5];
    const float* W2s   = (const float*)d_in[6];
    const float* W3    = (const float*)d_in[7];
    const float* W3p   = (const float*)d_in[8];
    const float* W3s   = (const float*)d_in[9];
    const float* W3t   = (const float*)d_in[10];
    const int* nbr1    = (const int*)d_in[11];
    const int* nbr2    = (const int*)d_in[12];
    const int* nbr3    = (const int*)d_in[13];
    const int* parent2 = (const int*)d_in[14];
    const int* parent3 = (const int*)d_in[15];
    const int* coords1 = (const int*)d_in[16];
    const int* coords2 = (const int*)d_in[17];

    const int N1 = in_sizes[0] / 80;
    const int N2 = in_sizes[1] / 48;
    const int N3 = in_sizes[2] / 16;

    float* out = (float*)d_out;
    float* o_points = out;                              // [N3,10]
    float* o_ppn1   = o_points + (size_t)N3 * 10;       // [N1,6]
    float* o_ppn2   = o_ppn1 + (size_t)N1 * 6;          // [N2,6]
    float* o_mask1  = o_ppn2 + (size_t)N2 * 6;          // [N1]
    float* o_mask2  = o_mask1 + (size_t)N1;             // [N2]

    char* wp = (char*)d_ws;
    auto alloc = [&](size_t bytes) -> char* {
        char* r = wp; wp += (bytes + 255) & ~(size_t)255; return r;
    };
    f16* WT1  = (f16*)alloc((size_t)80 * 28 * 160 * 2);
    f16* WT1s = (f16*)alloc((size_t)16 * 28 * 160 * 2);
    f16* WT2  = (f16*)alloc((size_t)48 * 28 * 96 * 2);
    f16* WT3  = (f16*)alloc((size_t)16 * 28 * 16 * 2);
    f16* WTp  = (f16*)alloc((size_t)16 * 28 * 16 * 2);
    float* s1 = (float*)alloc((size_t)(N1 + 1) * 2 * 4);
    float* s2 = (float*)alloc((size_t)(N2 + 1) * 2 * 4);
    size_t fe1 = (size_t)(N1 + 1) * 160, fe2 = (size_t)(N2 + 1) * 96, fe3 = (size_t)(N3 + 1) * 16;
    size_t maxF = fe1 > fe2 ? fe1 : fe2; if (fe3 > maxF) maxF = fe3;
    f16* Fa = (f16*)alloc(maxF * 2);
    f16* Ya = (f16*)alloc(maxF * 2);

    auto cdiv = [](long long a, long long b) { return (int)((a + b - 1) / b); };
    auto grid8 = [&](int nT) { return dim3(8 * cdiv(nT, 8)); };

    prep_all_kernel<<<512, 256, 0, stream>>>(W1, WT1, W1s, WT1s, W2, WT2,
                                             W3, WT3, W3p, W3s, W3t, WTp);

    // ---- level 1 (coarse, C=80): conv -> y1 (h|l), gather score -> s1 ----
    {
        int T = cdiv(N1 + 1, 128), Ts = cdiv(N1 + 1, 64);
        split_feat_kernel<80, true><<<cdiv((size_t)(N1 + 1) * 80, 256), 256, 0, stream>>>(
            feat1, nullptr, nullptr, Fa, N1);
        mfma_conv<80, 5, 2, 3, 8, EPI_SPLIT, 80><<<grid8(T), 512, 0, stream>>>(
            Fa, nbr1, WT1, nullptr, Ya, nullptr, nullptr, N1, T);
        mfma_conv<80, 1, 2, 3, 4, EPI_F32, 2><<<grid8(Ts), 256, 0, stream>>>(
            Ya, nbr1, WT1s, s1, nullptr, nullptr, nullptr, N1, Ts);
        ppn_finalize_kernel<<<cdiv(N1, 256), 256, 0, stream>>>(coords1, s1, o_ppn1, o_mask1, N1);
    }
    // ---- level 2 (mid, C=48): single conv with scatter-score epilogue ----
    {
        int T = cdiv(N2 + 1, 64);
        split_feat_kernel<48, true><<<cdiv((size_t)(N2 + 1) * 48, 256), 256, 0, stream>>>(
            feat2, o_mask1, parent2, Fa, N2);
        hipMemsetAsync(s2, 0, (size_t)(N2 + 1) * 2 * sizeof(float), stream);
        mfma_conv<48, 3, 2, 3, 4, EPI_SCAT, 2><<<grid8(T), 256, 0, stream>>>(
            Fa, nbr2, WT2, nullptr, nullptr, W2s, s2, N2, T);
        ppn_finalize_kernel<<<cdiv(N2, 256), 256, 0, stream>>>(coords2, s2, o_ppn2, o_mask2, N2);
    }
    // ---- level 3 (fine, C=16): plain f16, single-term ----
    {
        int T = cdiv(N3 + 1, 128);
        split_feat_kernel<16, false><<<cdiv((size_t)(N3 + 1) * 16, 256), 256, 0, stream>>>(
            feat3, o_mask2, parent3, Fa, N3);
        mfma_conv<16, 1, 4, 1, 8, EPI_F16, 16><<<grid8(T), 512, 0, stream>>>(
            Fa, nbr3, WT3, nullptr, Ya, nullptr, nullptr, N3, T);
        mfma_conv<16, 1, 4, 1, 8, EPI_F32, 10><<<grid8(T), 512, 0, stream>>>(
            Ya, nbr3, WTp, o_points, nullptr, nullptr, nullptr, N3, T);
    }
}

// Round 5
// 430.207 us; speedup vs baseline: 93.8267x; 93.8267x over previous
//
#include <hip/hip_runtime.h>

typedef _Float16 f16;
typedef _Float16 f16x8 __attribute__((ext_vector_type(8)));
typedef float f32x4 __attribute__((ext_vector_type(4)));

#define LN4 1.3862943611198906f

__device__ __forceinline__ void gl_lds16(const void* g, void* l) {
    typedef unsigned int u32;
    __builtin_amdgcn_global_load_lds(
        (const __attribute__((address_space(1))) u32*)(g),
        (__attribute__((address_space(3))) u32*)(l), 16, 0, 0);
}

// ===========================================================================
// Weight prep.
// 3-term layout: WT[d][tap][ h(CIN) | l(CIN) ] f16, d<CPAD, tap<28.
// plain layout:  WT[d][tap][ h(CIN) ] f16.
// ===========================================================================
__device__ void prep_split(int gid, int gsz, const float* __restrict__ W,
                           f16* __restrict__ dst, int CIN, int COUT, int CPAD)
{
    int total = CPAD * 28 * CIN;
    for (int i = gid; i < total; i += gsz) {
        int d = i / (28 * CIN);
        int rem = i - d * (28 * CIN);
        int tap = rem / CIN;
        int c = rem - tap * CIN;
        float v = (d < COUT && tap < 27) ? W[(size_t)(tap * CIN + c) * COUT + d] : 0.f;
        f16 h = (f16)v;
        size_t base = (size_t)d * (28 * 2 * CIN) + (size_t)tap * (2 * CIN);
        dst[base + c] = h;
        dst[base + CIN + c] = (f16)(v - (float)h);
    }
}

__device__ void prep_plain16(int gid, int gsz, const float* __restrict__ W,
                             f16* __restrict__ dst, int COUT)
{
    const int CIN = 16, CPAD = 16;
    int total = CPAD * 28 * CIN;
    for (int i = gid; i < total; i += gsz) {
        int d = i / (28 * CIN);
        int rem = i - d * (28 * CIN);
        int tap = rem / CIN;
        int c = rem - tap * CIN;
        float v = (d < COUT && tap < 27) ? W[(size_t)(tap * CIN + c) * COUT + d] : 0.f;
        dst[(size_t)d * (28 * CIN) + (size_t)tap * CIN + c] = (f16)v;
    }
}

__device__ void prep_pts(int gid, int gsz, const float* __restrict__ Wp,
                         const float* __restrict__ Ws, const float* __restrict__ Wt,
                         f16* __restrict__ dst)
{
    const int CIN = 16, CPAD = 16;
    int total = CPAD * 28 * CIN;
    for (int i = gid; i < total; i += gsz) {
        int d = i / (28 * CIN);
        int rem = i - d * (28 * CIN);
        int tap = rem / CIN;
        int c = rem - tap * CIN;
        float v = 0.f;
        if (tap < 27) {
            int kc = tap * CIN + c;
            if (d < 3)       v = Wp[(size_t)kc * 3 + d];
            else if (d < 5)  v = Ws[(size_t)kc * 2 + (d - 3)];
            else if (d < 10) v = Wt[(size_t)kc * 5 + (d - 5)];
        }
        dst[(size_t)d * (28 * CIN) + (size_t)tap * CIN + c] = (f16)v;
    }
}

__global__ __launch_bounds__(256) void prep_all_kernel(
    const float* W1, f16* WT1, const float* W2, f16* WT2,
    const float* W3, f16* WT3,
    const float* W3p, const float* W3s, const float* W3t, f16* WTp)
{
    int gid = blockIdx.x * 256 + threadIdx.x;
    int gsz = gridDim.x * 256;
    prep_split(gid, gsz, W1, WT1, 80, 80, 80);
    prep_split(gid, gsz, W2, WT2, 48, 48, 48);
    prep_plain16(gid, gsz, W3, WT3, 16);
    prep_pts(gid, gsz, W3p, W3s, W3t, WTp);
}

// ===========================================================================
// Feature splits. 3-term: rows [h|l]; plain: rows [h]. Sentinel row at n==N.
// ===========================================================================
template<int CIN, bool SPLIT>
__global__ __launch_bounds__(256) void split_feat_kernel(
    const float* __restrict__ f, const float* __restrict__ mask,
    const int* __restrict__ parent, f16* __restrict__ Fc, int N)
{
    int i = blockIdx.x * 256 + threadIdx.x;
    if (i >= (N + 1) * CIN) return;
    int n = i / CIN;
    int c = i - n * CIN;
    float v = 0.f;
    if (n < N) {
        v = f[i];
        if (mask != nullptr) v *= mask[parent[n]];
    }
    if (SPLIT) {
        f16 h = (f16)v;
        Fc[(size_t)n * (2 * CIN) + c] = h;
        Fc[(size_t)n * (2 * CIN) + CIN + c] = (f16)(v - (float)h);
    } else {
        Fc[(size_t)n * CIN + c] = (f16)v;
    }
}

__global__ __launch_bounds__(256) void ppn_finalize_kernel(
    const int* __restrict__ coords, const float* __restrict__ s,
    float* __restrict__ ppn, float* __restrict__ mask, int N)
{
    int n = blockIdx.x * 256 + threadIdx.x;
    if (n >= N) return;
    float s0 = s[(size_t)n * 2 + 0], s1 = s[(size_t)n * 2 + 1];
    ppn[(size_t)n * 6 + 0] = (float)coords[(size_t)n * 4 + 0];
    ppn[(size_t)n * 6 + 1] = (float)coords[(size_t)n * 4 + 1];
    ppn[(size_t)n * 6 + 2] = (float)coords[(size_t)n * 4 + 2];
    ppn[(size_t)n * 6 + 3] = (float)coords[(size_t)n * 4 + 3];
    ppn[(size_t)n * 6 + 4] = s0;
    ppn[(size_t)n * 6 + 5] = s1;
    mask[n] = (s1 - s0 > LN4) ? 1.0f : 0.0f;
}

// ===========================================================================
// MFMA gather-conv, direct-gather A fragments (no LDS for A!).
// A-frag per lane: row = band*16 + (lane&15), k-group = quad -> 16B global
// load straight into the MFMA operand registers. Sentinel row idx==N is a
// single hot cacheline (L1 broadcast).
// B: LDSB ? staged per 2-tap slab via global_load_lds (XOR-swizzled, 2 barriers
//           per slab) : read directly from global (tiny weights, NO barriers).
// Epilogues: F16 (plain out + sentinel row), F32 (cols<OUTC), SCAT (scatter
// y*Wsc[26-k] into sout[nbr] via guarded fp32 atomics; idx<N guard is
// ESSENTIAL — unguarded sentinel atomics serialize the whole device).
// ===========================================================================
enum { EPI_F16 = 1, EPI_F32 = 2, EPI_SCAT = 3 };

template<int CIN, int NCT, int NTERMS, int NW, int EPI, int OUTC, bool LDSB>
__global__ __launch_bounds__(NW * 64) void mfma_conv(
    const f16* __restrict__ F, const int* __restrict__ nbr,
    const f16* __restrict__ WT, float* __restrict__ outf,
    f16* __restrict__ oc, const float* __restrict__ Wsc,
    float* __restrict__ sout, int N, int nTiles)
{
    constexpr int BM = NW * 16;
    constexpr int BLK = NW * 64;
    constexpr int RE = (NTERMS == 3 ? 2 : 1) * CIN;   // f16 elems per tap-row
    constexpr int KB = (2 * CIN) / 32;                // K32 blocks per 2-tap slab
    constexpr int COUT = NCT * 16;
    constexpr int CPT = RE / 8;                       // 16B chunks per tap-row
    constexpr int CPR = 2 * CPT;                      // chunks per slab-row
    constexpr int PB = CPR * 16;                      // LDS B row pitch
    static_assert(CIN % 16 == 0 || CIN == 48 || CIN == 80, "CIN");
    static_assert(!LDSB || CPR % 8 == 0, "swizzle needs 8-chunk groups");

    __shared__ int idxS[BM * 28];
    __shared__ __align__(16) char BS[LDSB ? COUT * PB : 16];
    __shared__ float WsL[EPI == EPI_SCAT ? 27 * CIN * 2 : 1];

    const int t = threadIdx.x;
    const int lane = t & 63;
    const int l16 = lane & 15;
    const int quad = lane >> 4;
    const int band = t >> 6;

    int q8 = (nTiles + 7) >> 3;
    int tile = (blockIdx.x & 7) * q8 + (blockIdx.x >> 3);
    if (tile >= nTiles) return;
    const int m0 = tile * BM;

    for (int i = t; i < BM * 28; i += BLK) {
        int r = i / 28, tap = i - r * 28, row = m0 + r;
        idxS[i] = (row < N && tap < 27) ? nbr[(size_t)row * 27 + tap] : N;
    }
    if (EPI == EPI_SCAT)
        for (int i = t; i < 27 * CIN * 2; i += BLK) WsL[i] = Wsc[i];
    if (!LDSB) __syncthreads();

    const int arow = band * 16 + l16;

    f32x4 acc[NCT];
    #pragma unroll
    for (int ct = 0; ct < NCT; ++ct) acc[ct] = (f32x4){0.f, 0.f, 0.f, 0.f};

    for (int p = 0; p < 14; ++p) {
        if (LDSB) {
            __syncthreads();   // prior compute done (also covers idxS/WsL at p=0)
            for (int i = t; i < COUT * CPR; i += BLK) {
                int d = i / CPR, cs = i - d * CPR;
                int c = (cs & ~7) | ((cs ^ d) & 7);
                int tp = c / CPT, cc = c - tp * CPT;
                gl_lds16((const char*)WT +
                             (((size_t)d * 28 + 2 * p + tp) * RE + cc * 8) * 2,
                         BS + (size_t)i * 16);
            }
            __syncthreads();
        }
        // per-lane direct A fragments
        int idx0 = idxS[arow * 28 + 2 * p];
        int idx1 = idxS[arow * 28 + 2 * p + 1];
        f16x8 a_h[KB], a_l[KB];
        #pragma unroll
        for (int kb = 0; kb < KB; ++kb) {
            int ko = kb * 32 + quad * 8;
            int ts = ko / CIN, c2 = ko - ts * CIN;
            int idx = ts ? idx1 : idx0;
            const f16* ap = F + (size_t)idx * RE + c2;
            a_h[kb] = *(const f16x8*)ap;
            if (NTERMS == 3) a_l[kb] = *(const f16x8*)(ap + CIN);
        }
        #pragma unroll
        for (int kb = 0; kb < KB; ++kb) {
            int ko = kb * 32 + quad * 8;
            int ts = ko / CIN, c2 = ko - ts * CIN;
            #pragma unroll
            for (int ct = 0; ct < NCT; ++ct) {
                int drow = ct * 16 + l16;
                f16x8 b_h, b_l;
                if (LDSB) {
                    int ch = ts * CPT + c2 / 8;
                    int sb = (ch & ~7) | ((ch ^ drow) & 7);
                    b_h = *(const f16x8*)(BS + drow * PB + sb * 16);
                    if (NTERMS == 3) {
                        int chl = ch + CIN / 8;
                        int sbl = (chl & ~7) | ((chl ^ drow) & 7);
                        b_l = *(const f16x8*)(BS + drow * PB + sbl * 16);
                    }
                } else {
                    const f16* bp = WT + ((size_t)drow * 28 + 2 * p + ts) * RE + c2;
                    b_h = *(const f16x8*)bp;
                    if (NTERMS == 3) b_l = *(const f16x8*)(bp + CIN);
                }
                acc[ct] = __builtin_amdgcn_mfma_f32_16x16x32_f16(a_h[kb], b_h, acc[ct], 0, 0, 0);
                if (NTERMS == 3) {
                    acc[ct] = __builtin_amdgcn_mfma_f32_16x16x32_f16(a_l[kb], b_h, acc[ct], 0, 0, 0);
                    acc[ct] = __builtin_amdgcn_mfma_f32_16x16x32_f16(a_h[kb], b_l, acc[ct], 0, 0, 0);
                }
            }
        }
    }

    // ---- epilogues; D: row = quad*4+reg, col = lane&15 ----
    if (EPI == EPI_SCAT) {
        #pragma unroll 1
        for (int tap = 0; tap < 27; ++tap) {
            const float* w = &WsL[(26 - tap) * CIN * 2];
            float q0[4] = {}, q1[4] = {};
            #pragma unroll
            for (int ct = 0; ct < NCT; ++ct) {
                float w0 = w[(ct * 16 + l16) * 2 + 0];
                float w1 = w[(ct * 16 + l16) * 2 + 1];
                #pragma unroll
                for (int r = 0; r < 4; ++r) {
                    q0[r] += acc[ct][r] * w0;
                    q1[r] += acc[ct][r] * w1;
                }
            }
            #pragma unroll
            for (int m = 1; m < 16; m <<= 1) {
                #pragma unroll
                for (int r = 0; r < 4; ++r) {
                    q0[r] += __shfl_xor(q0[r], m);
                    q1[r] += __shfl_xor(q1[r], m);
                }
            }
            if (l16 < 8) {
                int r = l16 >> 1, j = l16 & 1;
                float v0 = (r == 0) ? q0[0] : (r == 1) ? q0[1] : (r == 2) ? q0[2] : q0[3];
                float v1 = (r == 0) ? q1[0] : (r == 1) ? q1[1] : (r == 2) ? q1[2] : q1[3];
                float v = (j == 0) ? v0 : v1;
                int idx = idxS[(band * 16 + quad * 4 + r) * 28 + tap];
                if (idx < N)                       // guard: sentinel atomics serialize!
                    atomicAdd(&sout[(size_t)idx * 2 + j], v);
            }
        }
    } else {
        #pragma unroll
        for (int ct = 0; ct < NCT; ++ct) {
            int col = ct * 16 + l16;
            #pragma unroll
            for (int r = 0; r < 4; ++r) {
                int row = m0 + band * 16 + quad * 4 + r;
                float v = acc[ct][r];
                if (EPI == EPI_F16) {
                    if (row < N) oc[(size_t)row * COUT + col] = (f16)v;
                    else if (row == N) oc[(size_t)row * COUT + col] = (f16)0.f;
                } else {  // EPI_F32
                    if (row < N && col < OUTC)
                        outf[(size_t)row * OUTC + col] = v;
                }
            }
        }
    }
}

// ===========================================================================
extern "C" void kernel_launch(void* const* d_in, const int* in_sizes, int n_in,
                              void* d_out, int out_size, void* d_ws, size_t ws_size,
                              hipStream_t stream)
{
    const float* feat1 = (const float*)d_in[0];
    const float* feat2 = (const float*)d_in[1];
    const float* feat3 = (const float*)d_in[2];
    const float* W1    = (const float*)d_in[3];
    const float* W1s   = (const float*)d_in[4];
    const float* W2    = (const float*)d_in[5];
    const float* W2s   = (const float*)d_in[6];
    const float* W3    = (const float*)d_in[7];
    const float* W3p   = (const float*)d_in[8];
    const float* W3s   = (const float*)d_in[9];
    const float* W3t   = (const float*)d_in[10];
    const int* nbr1    = (const int*)d_in[11];
    const int* nbr2    = (const int*)d_in[12];
    const int* nbr3    = (const int*)d_in[13];
    const int* parent2 = (const int*)d_in[14];
    const int* parent3 = (const int*)d_in[15];
    const int* coords1 = (const int*)d_in[16];
    const int* coords2 = (const int*)d_in[17];

    const int N1 = in_sizes[0] / 80;
    const int N2 = in_sizes[1] / 48;
    const int N3 = in_sizes[2] / 16;

    float* out = (float*)d_out;
    float* o_points = out;                              // [N3,10]
    float* o_ppn1   = o_points + (size_t)N3 * 10;       // [N1,6]
    float* o_ppn2   = o_ppn1 + (size_t)N1 * 6;          // [N2,6]
    float* o_mask1  = o_ppn2 + (size_t)N2 * 6;          // [N1]
    float* o_mask2  = o_mask1 + (size_t)N1;             // [N2]

    char* wp = (char*)d_ws;
    auto alloc = [&](size_t bytes) -> char* {
        char* r = wp; wp += (bytes + 255) & ~(size_t)255; return r;
    };
    f16* WT1 = (f16*)alloc((size_t)80 * 28 * 160 * 2);
    f16* WT2 = (f16*)alloc((size_t)48 * 28 * 96 * 2);
    f16* WT3 = (f16*)alloc((size_t)16 * 28 * 16 * 2);
    f16* WTp = (f16*)alloc((size_t)16 * 28 * 16 * 2);
    float* s1 = (float*)alloc((size_t)(N1 + 1) * 2 * 4);
    float* s2 = (float*)alloc((size_t)(N2 + 1) * 2 * 4);
    size_t fe1 = (size_t)(N1 + 1) * 160, fe2 = (size_t)(N2 + 1) * 96, fe3 = (size_t)(N3 + 1) * 16;
    size_t maxF = fe1 > fe2 ? fe1 : fe2; if (fe3 > maxF) maxF = fe3;
    f16* Fa = (f16*)alloc(maxF * 2);
    f16* Ya = (f16*)alloc(maxF * 2);

    auto cdiv = [](long long a, long long b) { return (int)((a + b - 1) / b); };
    auto grid8 = [&](int nT) { return dim3(8 * cdiv(nT, 8)); };

    prep_all_kernel<<<512, 256, 0, stream>>>(W1, WT1, W2, WT2, W3, WT3,
                                             W3p, W3s, W3t, WTp);

    // ---- level 1 (coarse, C=80): conv80 + scatter score -> s1 directly ----
    {
        int T = cdiv(N1 + 1, 64);
        split_feat_kernel<80, true><<<cdiv((size_t)(N1 + 1) * 80, 256), 256, 0, stream>>>(
            feat1, nullptr, nullptr, Fa, N1);
        hipMemsetAsync(s1, 0, (size_t)(N1 + 1) * 2 * sizeof(float), stream);
        mfma_conv<80, 5, 3, 4, EPI_SCAT, 2, true><<<grid8(T), 256, 0, stream>>>(
            Fa, nbr1, WT1, nullptr, nullptr, W1s, s1, N1, T);
        ppn_finalize_kernel<<<cdiv(N1, 256), 256, 0, stream>>>(coords1, s1, o_ppn1, o_mask1, N1);
    }
    // ---- level 2 (mid, C=48): conv48 + scatter score -> s2 directly ----
    {
        int T = cdiv(N2 + 1, 128);
        split_feat_kernel<48, true><<<cdiv((size_t)(N2 + 1) * 48, 256), 256, 0, stream>>>(
            feat2, o_mask1, parent2, Fa, N2);
        hipMemsetAsync(s2, 0, (size_t)(N2 + 1) * 2 * sizeof(float), stream);
        mfma_conv<48, 3, 3, 8, EPI_SCAT, 2, true><<<grid8(T), 512, 0, stream>>>(
            Fa, nbr2, WT2, nullptr, nullptr, W2s, s2, N2, T);
        ppn_finalize_kernel<<<cdiv(N2, 256), 256, 0, stream>>>(coords2, s2, o_ppn2, o_mask2, N2);
    }
    // ---- level 3 (fine, C=16): plain f16, direct-B, barrier-free ----
    {
        int T = cdiv(N3 + 1, 128);
        split_feat_kernel<16, false><<<cdiv((size_t)(N3 + 1) * 16, 256), 256, 0, stream>>>(
            feat3, o_mask2, parent3, Fa, N3);
        mfma_conv<16, 1, 1, 8, EPI_F16, 16, false><<<grid8(T), 512, 0, stream>>>(
            Fa, nbr3, WT3, nullptr, Ya, nullptr, nullptr, N3, T);
        mfma_conv<16, 1, 1, 8, EPI_F32, 10, false><<<grid8(T), 512, 0, stream>>>(
            Ya, nbr3, WTp, o_points, nullptr, nullptr, nullptr, N3, T);
    }
}